// Round 13
// baseline (76.410 us; speedup 1.0000x reference)
//
#include <hip/hip_runtime.h>
#include <hip/hip_bf16.h>
#include <hip/hip_fp16.h>
#include <math.h>

// Problem: N=50000 nodes, E=800000 edges, D=G=128.
// out[v,:] = elu( sum_{e: dst(e)=v} softmax_e(leaky(pd[dst]+ps[src]+b)) * hv[src(e),:] )
// pd[v] = nf[v]·W_edge[0:D] (+ b_edge), ps[v] = nf[v]·W_edge[D:2D]  (via MFMA, col 0/1
// of an extra B-tile), hv = leaky_relu(nf @ W_node + b_node) via bf16 MFMA.
// hv-GEMM and edge-binning fused (block-range dispatch); bucket sort + softmax +
// aggregation fused (per-bucket LDS pipeline, no ssw/offs/degv round-trip).
// Requires nN <= 65536 (src/dst packed in 16 bits) — holds for this problem.

#define BK_SHIFT 6
#define BK_CAP 2048
// BIN_CHUNK=4096 (196 blocks): fewer per-bucket reservation atomics; 1024 caused
// ~500-deep same-address atomic chains on bcnt and regressed 12 us (R10).
#define BIN_CHUNK 4096

using bf16x8 = __attribute__((ext_vector_type(8))) __bf16;
using f32x4 = __attribute__((ext_vector_type(4))) float;

static __device__ __forceinline__ unsigned pack_bf16(float x0, float x1) {
  unsigned u0 = (unsigned)__bfloat16_as_ushort(__float2bfloat16(x0));
  unsigned u1 = (unsigned)__bfloat16_as_ushort(__float2bfloat16(x1));
  return u0 | (u1 << 16);
}

// ---- one-time: Wn -> bf16 B-fragments (wsw); We -> bf16 B-fragments in cols 0,1
// of a single 16-col tile (wswE); zero bcnt (replaces in-graph hipMemsetAsync).
__global__ void wconv_kernel(const float* __restrict__ Wn, const float* __restrict__ We,
                             ushort* __restrict__ wsw, ushort* __restrict__ wswE,
                             int* __restrict__ bcnt, int nB) {
  int i = blockIdx.x * 256 + threadIdx.x;  // 0..16383
  if (i < nB) bcnt[i] = 0;
  {
    int j = i & 7, l = (i >> 3) & 63, ct = (i >> 9) & 7, kstep = i >> 12;
    int k = kstep * 32 + ((l >> 4) << 3) + j;
    int c = ct * 16 + (l & 15);
    wsw[i] = __bfloat16_as_ushort(__float2bfloat16(Wn[k * 128 + c]));
  }
  if (i < 2048) {  // We fragment: col0 = We[0:128] (pd), col1 = We[128:256] (ps)
    int j = i & 7, l = (i >> 3) & 63, kstep = i >> 9;
    int k = kstep * 32 + ((l >> 4) << 3) + j;
    int col = l & 15;
    float v = col == 0 ? We[k] : (col == 1 ? We[128 + k] : 0.f);
    wswE[i] = __bfloat16_as_ushort(__float2bfloat16(v));
  }
}

// -------- fused: [blocks 0..nBin) edge-binning  |  [nBin..) hv MFMA GEMM --------
// The two paths use disjoint pipes (VMEM/atomics vs MFMA/LDS) and overlap.
__global__ __launch_bounds__(256) void hv_bin_kernel(
    const float* __restrict__ nf, const ushort* __restrict__ wsw,
    const ushort* __restrict__ wswE, const float* __restrict__ bn,
    const float* __restrict__ be, unsigned* __restrict__ hv2,
    float* __restrict__ pd, float* __restrict__ ps, int nN,
    const int* __restrict__ src, const int* __restrict__ dst,
    int* __restrict__ bcnt, unsigned* __restrict__ inter, int nE, int nB, int nBin) {
  __shared__ unsigned shmem[64 * 64];  // 16KB: Atile (hv path) / cnt[1024] (bin path)
  int t = threadIdx.x;

  if ((int)blockIdx.x < nBin) {
    // ---------------- bin path: multisplit by dst>>6 into fixed-CAP slots ----------------
    int* cnt = (int*)shmem;
    for (int b = t; b < nB; b += 256) cnt[b] = 0;
    __syncthreads();
    int base = blockIdx.x * BIN_CHUNK;
    int dv[16];
#pragma unroll
    for (int k = 0; k < 16; ++k) {
      int e = base + t + k * 256;
      dv[k] = (e < nE) ? dst[e] : -1;
      if (dv[k] >= 0) atomicAdd(&cnt[dv[k] >> BK_SHIFT], 1);
    }
    __syncthreads();
    // reserve global bucket ranges; counter slot becomes this wg's running base
    for (int b = t; b < nB; b += 256) {
      int c = cnt[b];
      cnt[b] = c ? atomicAdd(&bcnt[b], c) : 0;
    }
    __syncthreads();
#pragma unroll
    for (int k = 0; k < 16; ++k) {
      int e = base + t + k * 256;
      if (e < nE) {
        int d = dv[k];
        int b = d >> BK_SHIFT;
        int pos = atomicAdd(&cnt[b], 1);
        if (pos < BK_CAP)
          inter[(size_t)b * BK_CAP + pos] = ((unsigned)src[e] << BK_SHIFT) | (unsigned)(d & 63);
      }
    }
    return;
  }

  // ---------------- hv path: MFMA GEMM (hv cols + pd/ps cols) ----------------
  unsigned* Atile = shmem;  // 64 rows x 256B of bf16, XOR-swizzled 16B slots
  int row0 = ((int)blockIdx.x - nBin) * 64;
#pragma unroll
  for (int ss = 0; ss < 4; ++ss) {
    int s = t + ss * 256;
    int r = s >> 4, sl = s & 15;
    int gr = row0 + r;
    float4 f0 = make_float4(0.f, 0.f, 0.f, 0.f), f1 = f0;
    if (gr < nN) {
      const float4* p = reinterpret_cast<const float4*>(nf + (size_t)gr * 128 + sl * 8);
      f0 = p[0];
      f1 = p[1];
    }
    uint4 pk;
    pk.x = pack_bf16(f0.x, f0.y);
    pk.y = pack_bf16(f0.z, f0.w);
    pk.z = pack_bf16(f1.x, f1.y);
    pk.w = pack_bf16(f1.z, f1.w);
    int byte = r * 256 + ((sl * 16) ^ ((r & 7) << 4));  // T2 swizzle vs 16-way conflict
    *reinterpret_cast<uint4*>(reinterpret_cast<char*>(Atile) + byte) = pk;
  }
  __syncthreads();
  int lane = t & 63, w = t >> 6;
  // MFMA: wave w owns rows w*16..w*16+15; 8 hv col-tiles + 1 edge-proj tile; K=128
  f32x4 acc[8], accE;
#pragma unroll
  for (int c = 0; c < 8; ++c) acc[c] = (f32x4){0.f, 0.f, 0.f, 0.f};
  accE = (f32x4){0.f, 0.f, 0.f, 0.f};
  int rl = w * 16 + (lane & 15);
  const char* abase = reinterpret_cast<const char*>(Atile) + rl * 256;
  int ksel = (lane >> 4) * 16;
#pragma unroll
  for (int kstep = 0; kstep < 4; ++kstep) {
    int kb = kstep * 64 + ksel;
    bf16x8 afrag = *reinterpret_cast<const bf16x8*>(abase + (kb ^ ((rl & 7) << 4)));
#pragma unroll
    for (int ct = 0; ct < 8; ++ct) {
      bf16x8 bfrag = *reinterpret_cast<const bf16x8*>(wsw + ((size_t)((kstep * 8 + ct) * 64 + lane)) * 8);
      acc[ct] = __builtin_amdgcn_mfma_f32_16x16x32_bf16(afrag, bfrag, acc[ct], 0, 0, 0);
    }
    bf16x8 bfragE = *reinterpret_cast<const bf16x8*>(wswE + ((size_t)(kstep * 64 + lane)) * 8);
    accE = __builtin_amdgcn_mfma_f32_16x16x32_bf16(afrag, bfragE, accE, 0, 0, 0);
  }
  // epilogue: D layout col=lane&15, row=(lane>>4)*4+reg
  int colbase = lane & 15;
  int rbase = row0 + w * 16 + ((lane >> 4) << 2);
  if (colbase < 2) {  // edge-proj columns: 0 -> pd (+bias), 1 -> ps
    float bev = be[0];
#pragma unroll
    for (int r = 0; r < 4; ++r) {
      int gr = rbase + r;
      if (gr < nN) {
        if (colbase == 0) pd[gr] = accE[r] + bev;
        else ps[gr] = accE[r];
      }
    }
  }
#pragma unroll
  for (int ct = 0; ct < 8; ++ct) {
    int col = ct * 16 + colbase;
    float bb = bn[col];
#pragma unroll
    for (int r = 0; r < 4; ++r) {
      float x = acc[ct][r] + bb;
      x = x > 0.f ? x : 0.01f * x;
      float y = __shfl_xor(x, 1);
      int gr = rbase + r;
      if (!(lane & 1) && gr < nN)
        hv2[(size_t)gr * 64 + ct * 8 + (colbase >> 1)] = pack_bf16(x, y);
    }
  }
}

// -------- fused phase 2: per-bucket sort + softmax + AGGREGATION (one kernel) --------
// Sorted (src, f32 weight) pairs live in LDS; 4 waves then aggregate 16 nodes each:
// per node, 16 hv2 row-gathers in flight, records via wave-uniform b64 LDS broadcast.
__global__ __launch_bounds__(256) void place_agg_kernel(
    const int* __restrict__ bcnt, const unsigned* __restrict__ inter,
    const float* __restrict__ pd, const float* __restrict__ ps,
    const unsigned* __restrict__ hv2, float* __restrict__ out, int nN) {
  __shared__ unsigned recs[BK_CAP];     // 8KB  input records
  __shared__ unsigned pw[BK_CAP * 2];   // 16KB sorted pairs: [2i]=src, [2i+1]=logit->weight
  __shared__ int cnt[64], cur[64], segst[64];
  __shared__ float part[256];
  __shared__ float mx[64], rsum[64];
  int b = blockIdx.x;
  int t = threadIdx.x;
  int cntE = min(bcnt[b], BK_CAP);
  for (int i = t; i < cntE; i += 256) recs[i] = inter[(size_t)b * BK_CAP + i];
  if (t < 64) cnt[t] = 0;
  __syncthreads();
  for (int i = t; i < cntE; i += 256) atomicAdd(&cnt[recs[i] & 63], 1);
  __syncthreads();
  if (t < 64) {  // wave-0 exclusive scan of the 64 per-dst counts
    int c = cnt[t];
    int incl = c;
#pragma unroll
    for (int o = 1; o < 64; o <<= 1) {
      int x = __shfl_up(incl, o);
      if (t >= o) incl += x;
    }
    int excl = incl - c;
    cur[t] = excl;
    segst[t] = excl;
  }
  __syncthreads();
  // scatter into sorted order; compute leaky logit (ps is L2-resident)
  for (int i = t; i < cntE; i += 256) {
    unsigned r = recs[i];
    int s = r >> BK_SHIFT, d = r & 63;
    float x = pd[b * 64 + d] + ps[s];
    x = x > 0.f ? x : 0.01f * x;
    int pos = atomicAdd(&cur[d], 1);
    pw[2 * pos] = (unsigned)s;
    pw[2 * pos + 1] = __float_as_uint(x);
  }
  __syncthreads();
  {  // parallel per-node max: 4 threads per node, stride-4
    int node = t & 63, q = t >> 6;
    int st = segst[node], c = cnt[node];
    float m = -1e30f;
    for (int i = st + q; i < st + c; i += 4) m = fmaxf(m, __uint_as_float(pw[2 * i + 1]));
    part[t] = m;
  }
  __syncthreads();
  if (t < 64) mx[t] = fmaxf(fmaxf(part[t], part[64 + t]), fmaxf(part[128 + t], part[192 + t]));
  __syncthreads();
  {  // parallel per-node sum of exp
    int node = t & 63, q = t >> 6;
    int st = segst[node], c = cnt[node];
    float m = mx[node];
    float ss = 0.f;
    for (int i = st + q; i < st + c; i += 4) ss += __expf(__uint_as_float(pw[2 * i + 1]) - m);
    part[t] = ss;
  }
  __syncthreads();
  if (t < 64) {
    float ss = part[t] + part[64 + t] + part[128 + t] + part[192 + t];
    rsum[t] = cnt[t] ? 1.f / ss : 0.f;
  }
  __syncthreads();
  {  // finalize: logit -> normalized weight (in place, f32)
    int node = t & 63, q = t >> 6;
    int st = segst[node], c = cnt[node];
    float m = mx[node], rv = rsum[node];
    for (int i = st + q; i < st + c; i += 4)
      pw[2 * i + 1] = __float_as_uint(__expf(__uint_as_float(pw[2 * i + 1]) - m) * rv);
  }
  __syncthreads();
  // ---------------- aggregation: wave w handles nodes w*16 .. w*16+15 ----------------
  int lane = t & 63, w = t >> 6;
  for (int nn = 0; nn < 16; ++nn) {
    int node = w * 16 + nn;
    int v = b * 64 + node;
    if (v >= nN) break;  // wave-uniform
    float2* out2 = reinterpret_cast<float2*>(out) + (size_t)v * 64 + lane;
    int c = cnt[node];
    if (c == 0) {  // no incoming edges: elu(0) = 0
      *out2 = make_float2(0.f, 0.f);
      continue;
    }
    int st = segst[node];
    float acc0 = 0.f, acc1 = 0.f;
    for (int i0 = 0; i0 < c; i0 += 16) {
      unsigned u[16];
      float wgt[16];
      unsigned pk[16];
#pragma unroll
      for (int j = 0; j < 16; ++j) {  // wave-uniform b64 LDS broadcast
        int idx = i0 + j;
        int ii = st + (idx < c ? idx : 0);
        uint2 pr = *reinterpret_cast<const uint2*>(&pw[2 * ii]);
        u[j] = pr.x;
        wgt[j] = idx < c ? __uint_as_float(pr.y) : 0.f;
      }
#pragma unroll
      for (int j = 0; j < 16; ++j) pk[j] = hv2[(u[j] << 6) + lane];  // 16 in flight
#pragma unroll
      for (int j = 0; j < 16; ++j) {
        acc0 += wgt[j] * __uint_as_float(pk[j] << 16);
        acc1 += wgt[j] * __uint_as_float(pk[j] & 0xffff0000u);
      }
    }
    // elu: exp(x)-1 for x<0 (expm1 unnecessary: cancellation region error ~ulp(1))
    float e0 = acc0 > 0.f ? acc0 : __expf(acc0) - 1.f;
    float e1 = acc1 > 0.f ? acc1 : __expf(acc1) - 1.f;
    *out2 = make_float2(e0, e1);
  }
}

extern "C" void kernel_launch(void* const* d_in, const int* in_sizes, int n_in,
                              void* d_out, int out_size, void* d_ws, size_t ws_size,
                              hipStream_t stream) {
  const float* nf = (const float*)d_in[0];
  const int* src = (const int*)d_in[1];
  const int* dst = (const int*)d_in[2];
  const float* We = (const float*)d_in[3];
  const float* be = (const float*)d_in[4];
  const float* Wn = (const float*)d_in[5];
  const float* bn = (const float*)d_in[6];
  float* out = (float*)d_out;
  int nN = in_sizes[0] / 128;
  int nE = in_sizes[1];
  int nB = (nN + 63) >> BK_SHIFT;
  int nBin = (nE + BIN_CHUNK - 1) / BIN_CHUNK;
  int nHV = (nN + 63) / 64;

  // workspace carve (~20 MB), 16B-aligned chunks first
  char* wsp = (char*)d_ws;
  unsigned* hv2 = (unsigned*)wsp;   wsp += (size_t)nN * 64 * 4;
  unsigned* inter = (unsigned*)wsp; wsp += (size_t)nB * BK_CAP * 4;
  ushort* wsw = (ushort*)wsp;       wsp += 16384 * 2;
  ushort* wswE = (ushort*)wsp;      wsp += 2048 * 2;
  float* pd = (float*)wsp;          wsp += (size_t)nN * 4;
  float* ps = (float*)wsp;          wsp += (size_t)nN * 4;
  int* bcnt = (int*)wsp;            wsp += (size_t)nB * 4;

  // wconv also zeroes bcnt (stream-ordered before the fused kernel's bin path).
  wconv_kernel<<<64, 256, 0, stream>>>(Wn, We, wsw, wswE, bcnt, nB);
  hv_bin_kernel<<<nBin + nHV, 256, 0, stream>>>(nf, wsw, wswE, bn, be, hv2, pd, ps, nN,
                                                src, dst, bcnt, inter, nE, nB, nBin);
  place_agg_kernel<<<nB, 256, 0, stream>>>(bcnt, inter, pd, ps, hv2, out, nN);
}

// Round 14
// 73.476 us; speedup vs baseline: 1.0399x; 1.0399x over previous
//
#include <hip/hip_runtime.h>
#include <hip/hip_bf16.h>
#include <hip/hip_fp16.h>
#include <math.h>

// Problem: N=50000 nodes, E=800000 edges, D=G=128.
// out[v,:] = elu( sum_{e: dst(e)=v} softmax_e(leaky(pd[dst]+ps[src]+b)) * hv[src(e),:] )
// pd[v] = nf[v]·W_edge[0:D] (+ b_edge), ps[v] = nf[v]·W_edge[D:2D]  (via MFMA, col 0/1
// of an extra B-tile), hv = leaky_relu(nf @ W_node + b_node) via bf16 MFMA.
// hv-GEMM and edge-binning fused (block-range dispatch); bucket sort + softmax +
// aggregation fused per bucket. place_agg uses 512 threads (8 waves) so the
// latency-bound gather phase has ~24 resident waves/CU (R13 at 4 waves: 21% occ).
// Requires nN <= 65536 (src/dst packed in 16 bits) — holds for this problem.

#define BK_SHIFT 6
#define BK_CAP 2048
// BIN_CHUNK=4096 (196 blocks): fewer per-bucket reservation atomics; 1024 caused
// ~500-deep same-address atomic chains on bcnt and regressed 12 us (R10).
#define BIN_CHUNK 4096

using bf16x8 = __attribute__((ext_vector_type(8))) __bf16;
using f32x4 = __attribute__((ext_vector_type(4))) float;

static __device__ __forceinline__ unsigned pack_bf16(float x0, float x1) {
  unsigned u0 = (unsigned)__bfloat16_as_ushort(__float2bfloat16(x0));
  unsigned u1 = (unsigned)__bfloat16_as_ushort(__float2bfloat16(x1));
  return u0 | (u1 << 16);
}

// ---- one-time: Wn -> bf16 B-fragments (wsw); We -> bf16 B-fragments in cols 0,1
// of a single 16-col tile (wswE); zero bcnt (replaces in-graph hipMemsetAsync).
__global__ void wconv_kernel(const float* __restrict__ Wn, const float* __restrict__ We,
                             ushort* __restrict__ wsw, ushort* __restrict__ wswE,
                             int* __restrict__ bcnt, int nB) {
  int i = blockIdx.x * 256 + threadIdx.x;  // 0..16383
  if (i < nB) bcnt[i] = 0;
  {
    int j = i & 7, l = (i >> 3) & 63, ct = (i >> 9) & 7, kstep = i >> 12;
    int k = kstep * 32 + ((l >> 4) << 3) + j;
    int c = ct * 16 + (l & 15);
    wsw[i] = __bfloat16_as_ushort(__float2bfloat16(Wn[k * 128 + c]));
  }
  if (i < 2048) {  // We fragment: col0 = We[0:128] (pd), col1 = We[128:256] (ps)
    int j = i & 7, l = (i >> 3) & 63, kstep = i >> 9;
    int k = kstep * 32 + ((l >> 4) << 3) + j;
    int col = l & 15;
    float v = col == 0 ? We[k] : (col == 1 ? We[128 + k] : 0.f);
    wswE[i] = __bfloat16_as_ushort(__float2bfloat16(v));
  }
}

// -------- fused: [blocks 0..nBin) edge-binning  |  [nBin..) hv MFMA GEMM --------
// The two paths use disjoint pipes (VMEM/atomics vs MFMA/LDS) and overlap.
__global__ __launch_bounds__(256) void hv_bin_kernel(
    const float* __restrict__ nf, const ushort* __restrict__ wsw,
    const ushort* __restrict__ wswE, const float* __restrict__ bn,
    const float* __restrict__ be, unsigned* __restrict__ hv2,
    float* __restrict__ pd, float* __restrict__ ps, int nN,
    const int* __restrict__ src, const int* __restrict__ dst,
    int* __restrict__ bcnt, unsigned* __restrict__ inter, int nE, int nB, int nBin) {
  __shared__ unsigned shmem[64 * 64];  // 16KB: Atile (hv path) / cnt[1024] (bin path)
  int t = threadIdx.x;

  if ((int)blockIdx.x < nBin) {
    // ---------------- bin path: multisplit by dst>>6 into fixed-CAP slots ----------------
    int* cnt = (int*)shmem;
    for (int b = t; b < nB; b += 256) cnt[b] = 0;
    __syncthreads();
    int base = blockIdx.x * BIN_CHUNK;
    int dv[16];
#pragma unroll
    for (int k = 0; k < 16; ++k) {
      int e = base + t + k * 256;
      dv[k] = (e < nE) ? dst[e] : -1;
      if (dv[k] >= 0) atomicAdd(&cnt[dv[k] >> BK_SHIFT], 1);
    }
    __syncthreads();
    // reserve global bucket ranges; counter slot becomes this wg's running base
    for (int b = t; b < nB; b += 256) {
      int c = cnt[b];
      cnt[b] = c ? atomicAdd(&bcnt[b], c) : 0;
    }
    __syncthreads();
#pragma unroll
    for (int k = 0; k < 16; ++k) {
      int e = base + t + k * 256;
      if (e < nE) {
        int d = dv[k];
        int b = d >> BK_SHIFT;
        int pos = atomicAdd(&cnt[b], 1);
        if (pos < BK_CAP)
          inter[(size_t)b * BK_CAP + pos] = ((unsigned)src[e] << BK_SHIFT) | (unsigned)(d & 63);
      }
    }
    return;
  }

  // ---------------- hv path: MFMA GEMM (hv cols + pd/ps cols) ----------------
  unsigned* Atile = shmem;  // 64 rows x 256B of bf16, XOR-swizzled 16B slots
  int row0 = ((int)blockIdx.x - nBin) * 64;
#pragma unroll
  for (int ss = 0; ss < 4; ++ss) {
    int s = t + ss * 256;
    int r = s >> 4, sl = s & 15;
    int gr = row0 + r;
    float4 f0 = make_float4(0.f, 0.f, 0.f, 0.f), f1 = f0;
    if (gr < nN) {
      const float4* p = reinterpret_cast<const float4*>(nf + (size_t)gr * 128 + sl * 8);
      f0 = p[0];
      f1 = p[1];
    }
    uint4 pk;
    pk.x = pack_bf16(f0.x, f0.y);
    pk.y = pack_bf16(f0.z, f0.w);
    pk.z = pack_bf16(f1.x, f1.y);
    pk.w = pack_bf16(f1.z, f1.w);
    int byte = r * 256 + ((sl * 16) ^ ((r & 7) << 4));  // T2 swizzle vs 16-way conflict
    *reinterpret_cast<uint4*>(reinterpret_cast<char*>(Atile) + byte) = pk;
  }
  __syncthreads();
  int lane = t & 63, w = t >> 6;
  // MFMA: wave w owns rows w*16..w*16+15; 8 hv col-tiles + 1 edge-proj tile; K=128
  f32x4 acc[8], accE;
#pragma unroll
  for (int c = 0; c < 8; ++c) acc[c] = (f32x4){0.f, 0.f, 0.f, 0.f};
  accE = (f32x4){0.f, 0.f, 0.f, 0.f};
  int rl = w * 16 + (lane & 15);
  const char* abase = reinterpret_cast<const char*>(Atile) + rl * 256;
  int ksel = (lane >> 4) * 16;
#pragma unroll
  for (int kstep = 0; kstep < 4; ++kstep) {
    int kb = kstep * 64 + ksel;
    bf16x8 afrag = *reinterpret_cast<const bf16x8*>(abase + (kb ^ ((rl & 7) << 4)));
#pragma unroll
    for (int ct = 0; ct < 8; ++ct) {
      bf16x8 bfrag = *reinterpret_cast<const bf16x8*>(wsw + ((size_t)((kstep * 8 + ct) * 64 + lane)) * 8);
      acc[ct] = __builtin_amdgcn_mfma_f32_16x16x32_bf16(afrag, bfrag, acc[ct], 0, 0, 0);
    }
    bf16x8 bfragE = *reinterpret_cast<const bf16x8*>(wswE + ((size_t)(kstep * 64 + lane)) * 8);
    accE = __builtin_amdgcn_mfma_f32_16x16x32_bf16(afrag, bfragE, accE, 0, 0, 0);
  }
  // epilogue: D layout col=lane&15, row=(lane>>4)*4+reg
  int colbase = lane & 15;
  int rbase = row0 + w * 16 + ((lane >> 4) << 2);
  if (colbase < 2) {  // edge-proj columns: 0 -> pd (+bias), 1 -> ps
    float bev = be[0];
#pragma unroll
    for (int r = 0; r < 4; ++r) {
      int gr = rbase + r;
      if (gr < nN) {
        if (colbase == 0) pd[gr] = accE[r] + bev;
        else ps[gr] = accE[r];
      }
    }
  }
#pragma unroll
  for (int ct = 0; ct < 8; ++ct) {
    int col = ct * 16 + colbase;
    float bb = bn[col];
#pragma unroll
    for (int r = 0; r < 4; ++r) {
      float x = acc[ct][r] + bb;
      x = x > 0.f ? x : 0.01f * x;
      float y = __shfl_xor(x, 1);
      int gr = rbase + r;
      if (!(lane & 1) && gr < nN)
        hv2[(size_t)gr * 64 + ct * 8 + (colbase >> 1)] = pack_bf16(x, y);
    }
  }
}

// -------- fused phase 2: per-bucket sort + softmax + AGGREGATION (512 threads) --------
// Sorted (src, f32 weight) pairs live in LDS; 8 waves aggregate 8 nodes each:
// per node, 16 hv2 row-gathers in flight, records via wave-uniform b64 LDS broadcast.
__global__ __launch_bounds__(512) void place_agg_kernel(
    const int* __restrict__ bcnt, const unsigned* __restrict__ inter,
    const float* __restrict__ pd, const float* __restrict__ ps,
    const unsigned* __restrict__ hv2, float* __restrict__ out, int nN) {
  __shared__ unsigned recs[BK_CAP];     // 8KB  input records
  __shared__ unsigned pw[BK_CAP * 2];   // 16KB sorted pairs: [2i]=src, [2i+1]=logit->weight
  __shared__ int cnt[64], cur[64], segst[64];
  __shared__ float part[512];
  __shared__ float mx[64], rsum[64];
  int b = blockIdx.x;
  int t = threadIdx.x;
  int cntE = min(bcnt[b], BK_CAP);
  for (int i = t; i < cntE; i += 512) recs[i] = inter[(size_t)b * BK_CAP + i];
  if (t < 64) cnt[t] = 0;
  __syncthreads();
  for (int i = t; i < cntE; i += 512) atomicAdd(&cnt[recs[i] & 63], 1);
  __syncthreads();
  if (t < 64) {  // wave-0 exclusive scan of the 64 per-dst counts
    int c = cnt[t];
    int incl = c;
#pragma unroll
    for (int o = 1; o < 64; o <<= 1) {
      int x = __shfl_up(incl, o);
      if (t >= o) incl += x;
    }
    int excl = incl - c;
    cur[t] = excl;
    segst[t] = excl;
  }
  __syncthreads();
  // scatter into sorted order; compute leaky logit (ps is L2-resident)
  for (int i = t; i < cntE; i += 512) {
    unsigned r = recs[i];
    int s = r >> BK_SHIFT, d = r & 63;
    float x = pd[b * 64 + d] + ps[s];
    x = x > 0.f ? x : 0.01f * x;
    int pos = atomicAdd(&cur[d], 1);
    pw[2 * pos] = (unsigned)s;
    pw[2 * pos + 1] = __float_as_uint(x);
  }
  __syncthreads();
  {  // parallel per-node max: 8 threads per node, stride-8
    int node = t & 63, q = t >> 6;
    int st = segst[node], c = cnt[node];
    float m = -1e30f;
    for (int i = st + q; i < st + c; i += 8) m = fmaxf(m, __uint_as_float(pw[2 * i + 1]));
    part[t] = m;
  }
  __syncthreads();
  if (t < 64) {
    float m = part[t];
#pragma unroll
    for (int q = 1; q < 8; ++q) m = fmaxf(m, part[q * 64 + t]);
    mx[t] = m;
  }
  __syncthreads();
  {  // parallel per-node sum of exp
    int node = t & 63, q = t >> 6;
    int st = segst[node], c = cnt[node];
    float m = mx[node];
    float ss = 0.f;
    for (int i = st + q; i < st + c; i += 8) ss += __expf(__uint_as_float(pw[2 * i + 1]) - m);
    part[t] = ss;
  }
  __syncthreads();
  if (t < 64) {
    float ss = part[t];
#pragma unroll
    for (int q = 1; q < 8; ++q) ss += part[q * 64 + t];
    rsum[t] = cnt[t] ? 1.f / ss : 0.f;
  }
  __syncthreads();
  {  // finalize: logit -> normalized weight (in place, f32)
    int node = t & 63, q = t >> 6;
    int st = segst[node], c = cnt[node];
    float m = mx[node], rv = rsum[node];
    for (int i = st + q; i < st + c; i += 8)
      pw[2 * i + 1] = __float_as_uint(__expf(__uint_as_float(pw[2 * i + 1]) - m) * rv);
  }
  __syncthreads();
  // ---------------- aggregation: wave w handles nodes w*8 .. w*8+7 ----------------
  int lane = t & 63, w = t >> 6;
  for (int nn = 0; nn < 8; ++nn) {
    int node = w * 8 + nn;
    int v = b * 64 + node;
    if (v >= nN) break;  // wave-uniform
    float2* out2 = reinterpret_cast<float2*>(out) + (size_t)v * 64 + lane;
    int c = cnt[node];
    if (c == 0) {  // no incoming edges: elu(0) = 0
      *out2 = make_float2(0.f, 0.f);
      continue;
    }
    int st = segst[node];
    float acc0 = 0.f, acc1 = 0.f;
    for (int i0 = 0; i0 < c; i0 += 16) {
      unsigned u[16];
      float wgt[16];
      unsigned pk[16];
#pragma unroll
      for (int j = 0; j < 16; ++j) {  // wave-uniform b64 LDS broadcast
        int idx = i0 + j;
        int ii = st + (idx < c ? idx : 0);
        uint2 pr = *reinterpret_cast<const uint2*>(&pw[2 * ii]);
        u[j] = pr.x;
        wgt[j] = idx < c ? __uint_as_float(pr.y) : 0.f;
      }
#pragma unroll
      for (int j = 0; j < 16; ++j) pk[j] = hv2[(u[j] << 6) + lane];  // 16 in flight
#pragma unroll
      for (int j = 0; j < 16; ++j) {
        acc0 += wgt[j] * __uint_as_float(pk[j] << 16);
        acc1 += wgt[j] * __uint_as_float(pk[j] & 0xffff0000u);
      }
    }
    // elu: exp(x)-1 for x<0 (expm1 unnecessary: cancellation region error ~ulp(1))
    float e0 = acc0 > 0.f ? acc0 : __expf(acc0) - 1.f;
    float e1 = acc1 > 0.f ? acc1 : __expf(acc1) - 1.f;
    *out2 = make_float2(e0, e1);
  }
}

extern "C" void kernel_launch(void* const* d_in, const int* in_sizes, int n_in,
                              void* d_out, int out_size, void* d_ws, size_t ws_size,
                              hipStream_t stream) {
  const float* nf = (const float*)d_in[0];
  const int* src = (const int*)d_in[1];
  const int* dst = (const int*)d_in[2];
  const float* We = (const float*)d_in[3];
  const float* be = (const float*)d_in[4];
  const float* Wn = (const float*)d_in[5];
  const float* bn = (const float*)d_in[6];
  float* out = (float*)d_out;
  int nN = in_sizes[0] / 128;
  int nE = in_sizes[1];
  int nB = (nN + 63) >> BK_SHIFT;
  int nBin = (nE + BIN_CHUNK - 1) / BIN_CHUNK;
  int nHV = (nN + 63) / 64;

  // workspace carve (~20 MB), 16B-aligned chunks first
  char* wsp = (char*)d_ws;
  unsigned* hv2 = (unsigned*)wsp;   wsp += (size_t)nN * 64 * 4;
  unsigned* inter = (unsigned*)wsp; wsp += (size_t)nB * BK_CAP * 4;
  ushort* wsw = (ushort*)wsp;       wsp += 16384 * 2;
  ushort* wswE = (ushort*)wsp;      wsp += 2048 * 2;
  float* pd = (float*)wsp;          wsp += (size_t)nN * 4;
  float* ps = (float*)wsp;          wsp += (size_t)nN * 4;
  int* bcnt = (int*)wsp;            wsp += (size_t)nB * 4;

  // wconv also zeroes bcnt (stream-ordered before the fused kernel's bin path).
  wconv_kernel<<<64, 256, 0, stream>>>(Wn, We, wsw, wswE, bcnt, nB);
  hv_bin_kernel<<<nBin + nHV, 256, 0, stream>>>(nf, wsw, wswE, bn, be, hv2, pd, ps, nN,
                                                src, dst, bcnt, inter, nE, nB, nBin);
  place_agg_kernel<<<nB, 512, 0, stream>>>(bcnt, inter, pd, ps, hv2, out, nN);
}

// Round 15
// 69.394 us; speedup vs baseline: 1.1011x; 1.0588x over previous
//
#include <hip/hip_runtime.h>
#include <hip/hip_bf16.h>
#include <hip/hip_fp16.h>
#include <math.h>

// Problem: N=50000 nodes, E=800000 edges, D=G=128.
// out[v,:] = elu( sum_{e: dst(e)=v} softmax_e(leaky(pd[dst]+ps[src]+b)) * hv[src(e),:] )
// pd/ps via MFMA (extra B-tile), hv = leaky_relu(nf @ W_node + b_node) via bf16 MFMA.
// hv-GEMM and edge-binning fused (block-range dispatch); bucket sort + softmax +
// aggregation fused per bucket. Buckets are 32 dst-nodes (BK_SHIFT=5): 1563 blocks
// x 512 threads -> 4 blocks/CU (thread-capped) = 32 waves/CU for the gather phase.
// Requires nN <= 65536 (src/dst packed in 16 bits) — holds for this problem.

#define BK_SHIFT 5
#define BK_NODES 32
#define BK_CAP 1024
// BIN_CHUNK=4096 (196 blocks): fewer per-bucket reservation atomics; 1024 caused
// ~500-deep same-address atomic chains on bcnt and regressed 12 us (R10).
#define BIN_CHUNK 4096

using bf16x8 = __attribute__((ext_vector_type(8))) __bf16;
using f32x4 = __attribute__((ext_vector_type(4))) float;

static __device__ __forceinline__ unsigned pack_bf16(float x0, float x1) {
  unsigned u0 = (unsigned)__bfloat16_as_ushort(__float2bfloat16(x0));
  unsigned u1 = (unsigned)__bfloat16_as_ushort(__float2bfloat16(x1));
  return u0 | (u1 << 16);
}

// ---- one-time: Wn -> bf16 B-fragments (wsw); We -> bf16 B-fragments in cols 0,1
// of a single 16-col tile (wswE); zero bcnt (replaces in-graph hipMemsetAsync).
__global__ void wconv_kernel(const float* __restrict__ Wn, const float* __restrict__ We,
                             ushort* __restrict__ wsw, ushort* __restrict__ wswE,
                             int* __restrict__ bcnt, int nB) {
  int i = blockIdx.x * 256 + threadIdx.x;  // 0..16383
  if (i < nB) bcnt[i] = 0;
  {
    int j = i & 7, l = (i >> 3) & 63, ct = (i >> 9) & 7, kstep = i >> 12;
    int k = kstep * 32 + ((l >> 4) << 3) + j;
    int c = ct * 16 + (l & 15);
    wsw[i] = __bfloat16_as_ushort(__float2bfloat16(Wn[k * 128 + c]));
  }
  if (i < 2048) {  // We fragment: col0 = We[0:128] (pd), col1 = We[128:256] (ps)
    int j = i & 7, l = (i >> 3) & 63, kstep = i >> 9;
    int k = kstep * 32 + ((l >> 4) << 3) + j;
    int col = l & 15;
    float v = col == 0 ? We[k] : (col == 1 ? We[128 + k] : 0.f);
    wswE[i] = __bfloat16_as_ushort(__float2bfloat16(v));
  }
}

// -------- fused: [blocks 0..nBin) edge-binning  |  [nBin..) hv MFMA GEMM --------
// The two paths use disjoint pipes (VMEM/atomics vs MFMA/LDS) and overlap.
__global__ __launch_bounds__(256) void hv_bin_kernel(
    const float* __restrict__ nf, const ushort* __restrict__ wsw,
    const ushort* __restrict__ wswE, const float* __restrict__ bn,
    const float* __restrict__ be, unsigned* __restrict__ hv2,
    float* __restrict__ pd, float* __restrict__ ps, int nN,
    const int* __restrict__ src, const int* __restrict__ dst,
    int* __restrict__ bcnt, unsigned* __restrict__ inter, int nE, int nB, int nBin) {
  __shared__ unsigned shmem[64 * 64];  // 16KB: Atile (hv path) / cnt[<=4096] (bin path)
  int t = threadIdx.x;

  if ((int)blockIdx.x < nBin) {
    // ---------------- bin path: multisplit by dst>>5 into fixed-CAP slots ----------------
    int* cnt = (int*)shmem;
    for (int b = t; b < nB; b += 256) cnt[b] = 0;
    __syncthreads();
    int base = blockIdx.x * BIN_CHUNK;
    int dv[16];
#pragma unroll
    for (int k = 0; k < 16; ++k) {
      int e = base + t + k * 256;
      dv[k] = (e < nE) ? dst[e] : -1;
      if (dv[k] >= 0) atomicAdd(&cnt[dv[k] >> BK_SHIFT], 1);
    }
    __syncthreads();
    // reserve global bucket ranges; counter slot becomes this wg's running base
    for (int b = t; b < nB; b += 256) {
      int c = cnt[b];
      cnt[b] = c ? atomicAdd(&bcnt[b], c) : 0;
    }
    __syncthreads();
#pragma unroll
    for (int k = 0; k < 16; ++k) {
      int e = base + t + k * 256;
      if (e < nE) {
        int d = dv[k];
        int b = d >> BK_SHIFT;
        int pos = atomicAdd(&cnt[b], 1);
        if (pos < BK_CAP)
          inter[(size_t)b * BK_CAP + pos] =
              ((unsigned)src[e] << BK_SHIFT) | (unsigned)(d & (BK_NODES - 1));
      }
    }
    return;
  }

  // ---------------- hv path: MFMA GEMM (hv cols + pd/ps cols) ----------------
  unsigned* Atile = shmem;  // 64 rows x 256B of bf16, XOR-swizzled 16B slots
  int row0 = ((int)blockIdx.x - nBin) * 64;
#pragma unroll
  for (int ss = 0; ss < 4; ++ss) {
    int s = t + ss * 256;
    int r = s >> 4, sl = s & 15;
    int gr = row0 + r;
    float4 f0 = make_float4(0.f, 0.f, 0.f, 0.f), f1 = f0;
    if (gr < nN) {
      const float4* p = reinterpret_cast<const float4*>(nf + (size_t)gr * 128 + sl * 8);
      f0 = p[0];
      f1 = p[1];
    }
    uint4 pk;
    pk.x = pack_bf16(f0.x, f0.y);
    pk.y = pack_bf16(f0.z, f0.w);
    pk.z = pack_bf16(f1.x, f1.y);
    pk.w = pack_bf16(f1.z, f1.w);
    int byte = r * 256 + ((sl * 16) ^ ((r & 7) << 4));  // T2 swizzle vs 16-way conflict
    *reinterpret_cast<uint4*>(reinterpret_cast<char*>(Atile) + byte) = pk;
  }
  __syncthreads();
  int lane = t & 63, w = t >> 6;
  // MFMA: wave w owns rows w*16..w*16+15; 8 hv col-tiles + 1 edge-proj tile; K=128
  f32x4 acc[8], accE;
#pragma unroll
  for (int c = 0; c < 8; ++c) acc[c] = (f32x4){0.f, 0.f, 0.f, 0.f};
  accE = (f32x4){0.f, 0.f, 0.f, 0.f};
  int rl = w * 16 + (lane & 15);
  const char* abase = reinterpret_cast<const char*>(Atile) + rl * 256;
  int ksel = (lane >> 4) * 16;
#pragma unroll
  for (int kstep = 0; kstep < 4; ++kstep) {
    int kb = kstep * 64 + ksel;
    bf16x8 afrag = *reinterpret_cast<const bf16x8*>(abase + (kb ^ ((rl & 7) << 4)));
#pragma unroll
    for (int ct = 0; ct < 8; ++ct) {
      bf16x8 bfrag = *reinterpret_cast<const bf16x8*>(wsw + ((size_t)((kstep * 8 + ct) * 64 + lane)) * 8);
      acc[ct] = __builtin_amdgcn_mfma_f32_16x16x32_bf16(afrag, bfrag, acc[ct], 0, 0, 0);
    }
    bf16x8 bfragE = *reinterpret_cast<const bf16x8*>(wswE + ((size_t)(kstep * 64 + lane)) * 8);
    accE = __builtin_amdgcn_mfma_f32_16x16x32_bf16(afrag, bfragE, accE, 0, 0, 0);
  }
  // epilogue: D layout col=lane&15, row=(lane>>4)*4+reg
  int colbase = lane & 15;
  int rbase = row0 + w * 16 + ((lane >> 4) << 2);
  if (colbase < 2) {  // edge-proj columns: 0 -> pd (+bias), 1 -> ps
    float bev = be[0];
#pragma unroll
    for (int r = 0; r < 4; ++r) {
      int gr = rbase + r;
      if (gr < nN) {
        if (colbase == 0) pd[gr] = accE[r] + bev;
        else ps[gr] = accE[r];
      }
    }
  }
#pragma unroll
  for (int ct = 0; ct < 8; ++ct) {
    int col = ct * 16 + colbase;
    float bb = bn[col];
#pragma unroll
    for (int r = 0; r < 4; ++r) {
      float x = acc[ct][r] + bb;
      x = x > 0.f ? x : 0.01f * x;
      float y = __shfl_xor(x, 1);
      int gr = rbase + r;
      if (!(lane & 1) && gr < nN)
        hv2[(size_t)gr * 64 + ct * 8 + (colbase >> 1)] = pack_bf16(x, y);
    }
  }
}

// -------- fused phase 2: per-bucket sort + softmax + AGGREGATION (512 threads) --------
// 32-node buckets; sorted (src, f32 weight) pairs in LDS; 8 waves aggregate 4 nodes
// each: 16 hv2 row-gathers in flight, records via wave-uniform b64 LDS broadcast.
__global__ __launch_bounds__(512) void place_agg_kernel(
    const int* __restrict__ bcnt, const unsigned* __restrict__ inter,
    const float* __restrict__ pd, const float* __restrict__ ps,
    const unsigned* __restrict__ hv2, float* __restrict__ out, int nN) {
  __shared__ unsigned recs[BK_CAP];            // 4KB input records
  __shared__ unsigned pw[BK_CAP * 2];          // 8KB sorted pairs: [2i]=src, [2i+1]=weight
  __shared__ int cnt[BK_NODES], cur[BK_NODES], segst[BK_NODES];
  __shared__ float part[512];
  __shared__ float mx[BK_NODES], rsum[BK_NODES];
  int b = blockIdx.x;
  int t = threadIdx.x;
  int cntE = min(bcnt[b], BK_CAP);
  for (int i = t; i < cntE; i += 512) recs[i] = inter[(size_t)b * BK_CAP + i];
  if (t < BK_NODES) cnt[t] = 0;
  __syncthreads();
  for (int i = t; i < cntE; i += 512) atomicAdd(&cnt[recs[i] & (BK_NODES - 1)], 1);
  __syncthreads();
  if (t < BK_NODES) {  // exclusive scan of the 32 per-dst counts (lanes 0..31 of wave 0)
    int c = cnt[t];
    int incl = c;
#pragma unroll
    for (int o = 1; o < BK_NODES; o <<= 1) {
      int x = __shfl_up(incl, o);
      if (t >= o) incl += x;
    }
    int excl = incl - c;
    cur[t] = excl;
    segst[t] = excl;
  }
  __syncthreads();
  // scatter into sorted order; compute leaky logit (ps is L2-resident)
  for (int i = t; i < cntE; i += 512) {
    unsigned r = recs[i];
    int s = r >> BK_SHIFT, d = r & (BK_NODES - 1);
    float x = pd[b * BK_NODES + d] + ps[s];
    x = x > 0.f ? x : 0.01f * x;
    int pos = atomicAdd(&cur[d], 1);
    pw[2 * pos] = (unsigned)s;
    pw[2 * pos + 1] = __float_as_uint(x);
  }
  __syncthreads();
  {  // parallel per-node max: 16 threads per node, stride-16
    int node = t & (BK_NODES - 1), q = t >> BK_SHIFT;
    int st = segst[node], c = cnt[node];
    float m = -1e30f;
    for (int i = st + q; i < st + c; i += 16) m = fmaxf(m, __uint_as_float(pw[2 * i + 1]));
    part[t] = m;
  }
  __syncthreads();
  if (t < BK_NODES) {
    float m = part[t];
#pragma unroll
    for (int q = 1; q < 16; ++q) m = fmaxf(m, part[q * BK_NODES + t]);
    mx[t] = m;
  }
  __syncthreads();
  {  // parallel per-node sum of exp
    int node = t & (BK_NODES - 1), q = t >> BK_SHIFT;
    int st = segst[node], c = cnt[node];
    float m = mx[node];
    float ss = 0.f;
    for (int i = st + q; i < st + c; i += 16) ss += __expf(__uint_as_float(pw[2 * i + 1]) - m);
    part[t] = ss;
  }
  __syncthreads();
  if (t < BK_NODES) {
    float ss = part[t];
#pragma unroll
    for (int q = 1; q < 16; ++q) ss += part[q * BK_NODES + t];
    rsum[t] = cnt[t] ? 1.f / ss : 0.f;
  }
  __syncthreads();
  {  // finalize: logit -> normalized weight (in place, f32)
    int node = t & (BK_NODES - 1), q = t >> BK_SHIFT;
    int st = segst[node], c = cnt[node];
    float m = mx[node], rv = rsum[node];
    for (int i = st + q; i < st + c; i += 16)
      pw[2 * i + 1] = __float_as_uint(__expf(__uint_as_float(pw[2 * i + 1]) - m) * rv);
  }
  __syncthreads();
  // ---------------- aggregation: wave w handles nodes w*4 .. w*4+3 ----------------
  int lane = t & 63, w = t >> 6;
  for (int nn = 0; nn < 4; ++nn) {
    int node = w * 4 + nn;
    int v = b * BK_NODES + node;
    if (v >= nN) break;  // wave-uniform
    float2* out2 = reinterpret_cast<float2*>(out) + (size_t)v * 64 + lane;
    int c = cnt[node];
    if (c == 0) {  // no incoming edges: elu(0) = 0
      *out2 = make_float2(0.f, 0.f);
      continue;
    }
    int st = segst[node];
    float acc0 = 0.f, acc1 = 0.f;
    for (int i0 = 0; i0 < c; i0 += 16) {
      unsigned u[16];
      float wgt[16];
      unsigned pk[16];
#pragma unroll
      for (int j = 0; j < 16; ++j) {  // wave-uniform b64 LDS broadcast
        int idx = i0 + j;
        int ii = st + (idx < c ? idx : 0);
        uint2 pr = *reinterpret_cast<const uint2*>(&pw[2 * ii]);
        u[j] = pr.x;
        wgt[j] = idx < c ? __uint_as_float(pr.y) : 0.f;
      }
#pragma unroll
      for (int j = 0; j < 16; ++j) pk[j] = hv2[(u[j] << 6) + lane];  // 16 in flight
#pragma unroll
      for (int j = 0; j < 16; ++j) {
        acc0 += wgt[j] * __uint_as_float(pk[j] << 16);
        acc1 += wgt[j] * __uint_as_float(pk[j] & 0xffff0000u);
      }
    }
    // elu: exp(x)-1 for x<0 (expm1 unnecessary: cancellation region error ~ulp(1))
    float e0 = acc0 > 0.f ? acc0 : __expf(acc0) - 1.f;
    float e1 = acc1 > 0.f ? acc1 : __expf(acc1) - 1.f;
    *out2 = make_float2(e0, e1);
  }
}

extern "C" void kernel_launch(void* const* d_in, const int* in_sizes, int n_in,
                              void* d_out, int out_size, void* d_ws, size_t ws_size,
                              hipStream_t stream) {
  const float* nf = (const float*)d_in[0];
  const int* src = (const int*)d_in[1];
  const int* dst = (const int*)d_in[2];
  const float* We = (const float*)d_in[3];
  const float* be = (const float*)d_in[4];
  const float* Wn = (const float*)d_in[5];
  const float* bn = (const float*)d_in[6];
  float* out = (float*)d_out;
  int nN = in_sizes[0] / 128;
  int nE = in_sizes[1];
  int nB = (nN + BK_NODES - 1) >> BK_SHIFT;
  int nBin = (nE + BIN_CHUNK - 1) / BIN_CHUNK;
  int nHV = (nN + 63) / 64;

  // workspace carve (~20 MB), 16B-aligned chunks first
  char* wsp = (char*)d_ws;
  unsigned* hv2 = (unsigned*)wsp;   wsp += (size_t)nN * 64 * 4;
  unsigned* inter = (unsigned*)wsp; wsp += (size_t)nB * BK_CAP * 4;
  ushort* wsw = (ushort*)wsp;       wsp += 16384 * 2;
  ushort* wswE = (ushort*)wsp;      wsp += 2048 * 2;
  float* pd = (float*)wsp;          wsp += (size_t)nN * 4;
  float* ps = (float*)wsp;          wsp += (size_t)nN * 4;
  int* bcnt = (int*)wsp;            wsp += (size_t)nB * 4;

  // wconv also zeroes bcnt (stream-ordered before the fused kernel's bin path).
  wconv_kernel<<<64, 256, 0, stream>>>(Wn, We, wsw, wswE, bcnt, nB);
  hv_bin_kernel<<<nBin + nHV, 256, 0, stream>>>(nf, wsw, wswE, bn, be, hv2, pd, ps, nN,
                                                src, dst, bcnt, inter, nE, nB, nBin);
  place_agg_kernel<<<nB, 512, 0, stream>>>(bcnt, inter, pd, ps, hv2, out, nN);
}